// Round 10
// baseline (394.613 us; speedup 1.0000x reference)
//
#include <hip/hip_runtime.h>
#include <hip/hip_fp16.h>
#include <cstddef>
#include <cstdint>

// Sinkformer attention, B=2 H=12 S=1024 D=64, fp32 in/out.
// v6: persistent-Sinkhorn. P = exp(QK^T/8) computed ONCE per 128x128 tile and
// held in REGISTERS (f32x4[2][4][4], 2 tiles/block); all 6 Sinkhorn reduction
// passes reuse it with hand-rolled grid barriers in ONE kernel (k_sink).
// Co-residency: grid 768 = 3 blocks/CU vs capacity 4/CU (__launch_bounds__(256,4),
// LDS 38KB) -- sanctioned manual-capacity pattern, 256-block slack.
// Cross-XCD visibility: device-scope atomicAdd for partials; agent-scope atomic
// loads for readback; monotonic-counter barrier (acq_rel add + acquire spin).
//   v0=rd0=rowsum(P); v1=cs0=colsum(P^T a1); v2=rd1=P b1; v3=cs1; v4=rd2; v5=cs2
//   k_final (r9, proven): attn = P*a3*(1/cs2); out = attn @ V.

#define NH 24
#define SEQ 1024
#define HD 64
#define NHS (NH * SEQ)
#define GRID_SINK 768

typedef _Float16 f16x8 __attribute__((ext_vector_type(8)));
typedef float f32x4 __attribute__((ext_vector_type(4)));

__device__ __forceinline__ float aload(float* p) {
  return __hip_atomic_load(p, __ATOMIC_RELAXED, __HIP_MEMORY_SCOPE_AGENT);
}
__device__ __forceinline__ void gbar(unsigned* cnt, unsigned target) {
  __syncthreads();  // all waves' atomics drained (vmcnt(0) before s_barrier)
  if (threadIdx.x == 0) {
    __hip_atomic_fetch_add(cnt, 1u, __ATOMIC_ACQ_REL, __HIP_MEMORY_SCOPE_AGENT);
    while (__hip_atomic_load(cnt, __ATOMIC_ACQUIRE, __HIP_MEMORY_SCOPE_AGENT) < target)
      __builtin_amdgcn_s_sleep(2);
  }
  __syncthreads();
}

// prep: flat grid 2304 = 3*768. z=0: Q->Q16 (+zero v0..v5 and barrier counter),
// z=1: K->K16, z=2: V->Vt16 (transpose via LDS).
__global__ __launch_bounds__(256) void k_prep(const float* __restrict__ q,
                                              const float* __restrict__ kin,
                                              const float* __restrict__ v,
                                              __half* __restrict__ q16,
                                              __half* __restrict__ k16,
                                              __half* __restrict__ vt16,
                                              float* __restrict__ zvec) {
  const int b = blockIdx.x;
  const int z = b / 768;
  const int bb = b - z * 768;
  const int t = threadIdx.x;
  if (z < 2) {
    const float* src = z ? kin : q;
    __half* dst = z ? k16 : q16;
    size_t u = ((size_t)bb * 256 + t) * 8;
    const float4* s4 = (const float4*)(src + u);
    float4 a = s4[0], c = s4[1];
    f16x8 h;
    h[0] = (_Float16)a.x; h[1] = (_Float16)a.y; h[2] = (_Float16)a.z; h[3] = (_Float16)a.w;
    h[4] = (_Float16)c.x; h[5] = (_Float16)c.y; h[6] = (_Float16)c.z; h[7] = (_Float16)c.w;
    *(f16x8*)(dst + u) = h;
    if (z == 0) {
      int gid = bb * 256 + t;
      if (gid < 6 * NHS) zvec[gid] = 0.f;            // rd0,cs0,rd1,cs1,rd2,cs2
      else if (gid == 6 * NHS) *(unsigned*)(zvec + 6 * NHS) = 0u;  // barrier counter
    }
  } else {
    __shared__ float ld[64][33];
    const int h = bb >> 5, s0 = (bb & 31) << 5;  // 32-row slab of V
    const float* Vh = v + (size_t)h * SEQ * HD;
#pragma unroll
    for (int it = 0; it < 2; ++it) {
      int f = t + (it << 8);
      int r = f >> 4, c4 = (f & 15) << 2;
      float4 vv = *(const float4*)(Vh + (size_t)(s0 + r) * HD + c4);
      ld[c4 + 0][r] = vv.x; ld[c4 + 1][r] = vv.y;
      ld[c4 + 2][r] = vv.z; ld[c4 + 3][r] = vv.w;
    }
    __syncthreads();
    int d = t >> 2, sg = (t & 3) << 3;
    f16x8 h8;
#pragma unroll
    for (int i = 0; i < 8; ++i) h8[i] = (_Float16)ld[d][sg + i];
    *(f16x8*)(vt16 + (size_t)h * HD * SEQ + (size_t)d * SEQ + s0 + sg) = h8;
  }
}

// Persistent Sinkhorn. 768 blocks x 2 tiles (128x128) each; 4 waves of 64x64
// quadrants per tile. P lives in registers across all 6 passes.
__global__ __launch_bounds__(256, 4) void k_sink(const __half* __restrict__ q16,
                                                 const __half* __restrict__ k16,
                                                 float* __restrict__ vec,
                                                 unsigned* __restrict__ cnt) {
  __shared__ __align__(16) __half ks[2][128][72];   // 36.9 KB
  __shared__ float ws_[2][128];
  const int bid = blockIdx.x;
  const int t = threadIdx.x;
  const int w = t >> 6, lane = t & 63;
  const int ln = lane & 15, ko = lane >> 4;
  const int rb = (w & 1) << 6, cb = (w >> 1) << 6;

  int hh[2], r0[2], c0[2];
#pragma unroll
  for (int u = 0; u < 2; ++u) {
    int b2 = bid + u * GRID_SINK;
    int swz = (b2 & 7) * 192 + (b2 >> 3);   // 1536 tiles, XCD-grouped, bijective
    hh[u] = swz >> 6;
    r0[u] = ((swz >> 3) & 7) << 7;
    c0[u] = (swz & 7) << 7;
  }

  // ---- phase 0: stage K, QK^T via MFMA, exp -> P in registers ----
#pragma unroll
  for (int u = 0; u < 2; ++u) {
    const __half* kh = k16 + ((size_t)hh[u] << 16);
#pragma unroll
    for (int it = 0; it < 4; ++it) {
      int f = t + (it << 8);
      int row = f >> 3, c8 = (f & 7) << 3;
      *(f16x8*)&ks[u][row][c8] = *(const f16x8*)(kh + (size_t)(c0[u] + row) * HD + c8);
    }
  }
  __syncthreads();

  f32x4 p[2][4][4] = {};
#pragma unroll
  for (int u = 0; u < 2; ++u) {
    const __half* qh = q16 + ((size_t)hh[u] << 16);
    f16x8 af[4][2];
#pragma unroll
    for (int m = 0; m < 4; ++m)
#pragma unroll
      for (int kk = 0; kk < 2; ++kk)
        af[m][kk] = *(const f16x8*)(qh + (size_t)(r0[u] + rb + m * 16 + ln) * HD + kk * 32 + ko * 8);
#pragma unroll
    for (int kk = 0; kk < 2; ++kk) {
      f16x8 bf[4];
#pragma unroll
      for (int n = 0; n < 4; ++n)
        bf[n] = *(const f16x8*)&ks[u][cb + n * 16 + ln][kk * 32 + ko * 8];
#pragma unroll
      for (int m = 0; m < 4; ++m)
#pragma unroll
        for (int n = 0; n < 4; ++n)
          p[u][m][n] = __builtin_amdgcn_mfma_f32_16x16x32_f16(af[m][kk], bf[n], p[u][m][n], 0, 0, 0);
    }
  }
#pragma unroll
  for (int u = 0; u < 2; ++u)
#pragma unroll
    for (int m = 0; m < 4; ++m)
#pragma unroll
      for (int n = 0; n < 4; ++n)
#pragma unroll
        for (int r = 0; r < 4; ++r)
          p[u][m][n][r] = __expf(p[u][m][n][r] * 0.125f);

  float* v0 = vec;             // rd0
  float* v1 = vec + 1 * NHS;   // cs0
  float* v2 = vec + 2 * NHS;   // rd1
  float* v3 = vec + 3 * NHS;   // cs1
  float* v4 = vec + 4 * NHS;   // rd2
  float* v5 = vec + 5 * NHS;   // cs2

  // col pass: a = mu/src_rd[row]; dst_cs_j += P_ij * a_i
  auto colpass = [&](float* src_rd, float* dst_cs) {
    if (t < 128) {
      ws_[0][t] = (1.0f / 1024.0f) / aload(&src_rd[hh[0] * SEQ + r0[0] + t]);
      ws_[1][t] = (1.0f / 1024.0f) / aload(&src_rd[hh[1] * SEQ + r0[1] + t]);
    }
    __syncthreads();
#pragma unroll
    for (int u = 0; u < 2; ++u)
#pragma unroll
      for (int n = 0; n < 4; ++n) {
        float s = 0.f;
#pragma unroll
        for (int m = 0; m < 4; ++m)
#pragma unroll
          for (int r = 0; r < 4; ++r)
            s += p[u][m][n][r] * ws_[u][rb + m * 16 + (ko << 2) + r];
        s += __shfl_xor(s, 16);
        s += __shfl_xor(s, 32);
        if (lane < 16) atomicAdd(&dst_cs[hh[u] * SEQ + c0[u] + cb + n * 16 + ln], s);
      }
  };
  // row pass: b = nu/src_cs[col]; dst_rd_i += P_ij * b_j
  auto rowpass = [&](float* src_cs, float* dst_rd) {
    if (t < 128) {
      ws_[0][t] = (1.0f / 1024.0f) / aload(&src_cs[hh[0] * SEQ + c0[0] + t]);
      ws_[1][t] = (1.0f / 1024.0f) / aload(&src_cs[hh[1] * SEQ + c0[1] + t]);
    }
    __syncthreads();
#pragma unroll
    for (int u = 0; u < 2; ++u)
#pragma unroll
      for (int m = 0; m < 4; ++m)
#pragma unroll
        for (int r = 0; r < 4; ++r) {
          float s = p[u][m][0][r] * ws_[u][cb + ln]
                  + p[u][m][1][r] * ws_[u][cb + 16 + ln]
                  + p[u][m][2][r] * ws_[u][cb + 32 + ln]
                  + p[u][m][3][r] * ws_[u][cb + 48 + ln];
          s += __shfl_xor(s, 1, 16); s += __shfl_xor(s, 2, 16);
          s += __shfl_xor(s, 4, 16); s += __shfl_xor(s, 8, 16);
          if (ln == 0) atomicAdd(&dst_rd[hh[u] * SEQ + r0[u] + rb + m * 16 + (ko << 2) + r], s);
        }
  };

  // ---- pass 1: rd0 = rowsum(P) ----
#pragma unroll
  for (int u = 0; u < 2; ++u)
#pragma unroll
    for (int m = 0; m < 4; ++m)
#pragma unroll
      for (int r = 0; r < 4; ++r) {
        float s = p[u][m][0][r] + p[u][m][1][r] + p[u][m][2][r] + p[u][m][3][r];
        s += __shfl_xor(s, 1, 16); s += __shfl_xor(s, 2, 16);
        s += __shfl_xor(s, 4, 16); s += __shfl_xor(s, 8, 16);
        if (ln == 0) atomicAdd(&v0[hh[u] * SEQ + r0[u] + rb + m * 16 + (ko << 2) + r], s);
      }
  gbar(cnt, 1 * GRID_SINK);
  colpass(v0, v1);  gbar(cnt, 2 * GRID_SINK);   // cs0 (a1 weights)
  rowpass(v1, v2);  gbar(cnt, 3 * GRID_SINK);   // rd1 (b1 weights)
  colpass(v2, v3);  gbar(cnt, 4 * GRID_SINK);   // cs1
  rowpass(v3, v4);  gbar(cnt, 5 * GRID_SINK);   // rd2
  colpass(v4, v5);                              // cs2 (kernel-end release)
}

// Final, pipelined (r9, proven): 16 rows/block, 4 waves. Per 128-col chunk
// (ONE barrier): [prefetch K/V frags c+1] [exp/scale sacc(c) -> ps16[c&1]] BAR
// [attn store] [PV(c): A=ps16, B=vf regs] [QK(c+1) -> sacc].
__global__ __launch_bounds__(256) void k_final(const __half* __restrict__ q16,
                                               const __half* __restrict__ k16,
                                               const __half* __restrict__ vt16,
                                               const float* __restrict__ rd2,
                                               const float* __restrict__ cs2,
                                               float* __restrict__ attn,
                                               float* __restrict__ out) {
  __shared__ __align__(16) __half ps16[2][16][136];
  __shared__ float binv[1024];
  __shared__ float a_s[16];
  const int bid = blockIdx.x;
  const int swz = (bid & 7) * 192 + (bid >> 3);   // bijective
  const int h = swz >> 6;
  const int rblk = swz & 63;
  const int t = threadIdx.x;
  const int w = t >> 6, lane = t & 63, ln = lane & 15, ko = lane >> 4;

#pragma unroll
  for (int i = 0; i < 4; ++i) {
    int idx = t + (i << 8);
    binv[idx] = 1.0f / cs2[h * SEQ + idx];
  }
  if (t < 16) a_s[t] = (1.0f / 1024.0f) / rd2[h * SEQ + rblk * 16 + t];

  const __half* qh = q16 + ((size_t)h << 16);
  const __half* kh = k16 + ((size_t)h << 16);
  const __half* vth = vt16 + ((size_t)h << 16);
  f16x8 aq[2];
#pragma unroll
  for (int kk = 0; kk < 2; ++kk)
    aq[kk] = *(const f16x8*)(qh + (size_t)(rblk * 16 + ln) * HD + kk * 32 + ko * 8);

  const int cw = w << 5;   // wave's 32-col QK slice within the chunk
  const int dw = w << 4;   // wave's 16-d PV slice

  f16x8 kf00, kf01, kf10, kf11;
  kf00 = *(const f16x8*)(kh + (size_t)(cw + ln) * HD + ko * 8);
  kf01 = *(const f16x8*)(kh + (size_t)(cw + 16 + ln) * HD + ko * 8);
  kf10 = *(const f16x8*)(kh + (size_t)(cw + ln) * HD + 32 + ko * 8);
  kf11 = *(const f16x8*)(kh + (size_t)(cw + 16 + ln) * HD + 32 + ko * 8);
  f16x8 vf0, vf1, vf2, vf3;
  {
    const __half* vb = vth + (size_t)(dw + ln) * SEQ;
    vf0 = *(const f16x8*)(vb + ko * 8);
    vf1 = *(const f16x8*)(vb + 32 + ko * 8);
    vf2 = *(const f16x8*)(vb + 64 + ko * 8);
    vf3 = *(const f16x8*)(vb + 96 + ko * 8);
  }
  f32x4 sacc0 = {}, sacc1 = {};
  sacc0 = __builtin_amdgcn_mfma_f32_16x16x32_f16(aq[0], kf00, sacc0, 0, 0, 0);
  sacc1 = __builtin_amdgcn_mfma_f32_16x16x32_f16(aq[0], kf01, sacc1, 0, 0, 0);
  sacc0 = __builtin_amdgcn_mfma_f32_16x16x32_f16(aq[1], kf10, sacc0, 0, 0, 0);
  sacc1 = __builtin_amdgcn_mfma_f32_16x16x32_f16(aq[1], kf11, sacc1, 0, 0, 0);
  f32x4 acc_o = {};
  __syncthreads();  // binv / a_s ready

  for (int c = 0; c < 8; ++c) {
    const int j0 = c << 7;
    const int buf = c & 1;
    f16x8 kn00, kn01, kn10, kn11, vn0, vn1, vn2, vn3;
    if (c < 7) {
      const __half* kb = kh + (size_t)(j0 + 128) * HD;
      kn00 = *(const f16x8*)(kb + (size_t)(cw + ln) * HD + ko * 8);
      kn01 = *(const f16x8*)(kb + (size_t)(cw + 16 + ln) * HD + ko * 8);
      kn10 = *(const f16x8*)(kb + (size_t)(cw + ln) * HD + 32 + ko * 8);
      kn11 = *(const f16x8*)(kb + (size_t)(cw + 16 + ln) * HD + 32 + ko * 8);
      const __half* vb = vth + (size_t)(dw + ln) * SEQ + j0 + 128;
      vn0 = *(const f16x8*)(vb + ko * 8);
      vn1 = *(const f16x8*)(vb + 32 + ko * 8);
      vn2 = *(const f16x8*)(vb + 64 + ko * 8);
      vn3 = *(const f16x8*)(vb + 96 + ko * 8);
    }
#pragma unroll
    for (int r = 0; r < 4; ++r) {
      int row = (ko << 2) + r;
      int cA = cw + ln, cB = cw + 16 + ln;
      ps16[buf][row][cA] = __float2half(__expf(sacc0[r] * 0.125f) * a_s[row] * binv[j0 + cA]);
      ps16[buf][row][cB] = __float2half(__expf(sacc1[r] * 0.125f) * a_s[row] * binv[j0 + cB]);
    }
    __syncthreads();
    {
      int arow = t >> 4, cg = (t & 15) << 3;
      f16x8 hv = *(const f16x8*)&ps16[buf][arow][cg];
      f32x4 o0, o1;
#pragma unroll
      for (int i = 0; i < 4; ++i) { o0[i] = (float)hv[i]; o1[i] = (float)hv[4 + i]; }
      float* ap = attn + (size_t)(h * SEQ + rblk * 16 + arow) * SEQ + j0 + cg;
      *(f32x4*)ap = o0;
      *(f32x4*)(ap + 4) = o1;
    }
    {
      f16x8 pa;
      pa = *(const f16x8*)&ps16[buf][ln][ko * 8];
      acc_o = __builtin_amdgcn_mfma_f32_16x16x32_f16(pa, vf0, acc_o, 0, 0, 0);
      pa = *(const f16x8*)&ps16[buf][ln][32 + ko * 8];
      acc_o = __builtin_amdgcn_mfma_f32_16x16x32_f16(pa, vf1, acc_o, 0, 0, 0);
      pa = *(const f16x8*)&ps16[buf][ln][64 + ko * 8];
      acc_o = __builtin_amdgcn_mfma_f32_16x16x32_f16(pa, vf2, acc_o, 0, 0, 0);
      pa = *(const f16x8*)&ps16[buf][ln][96 + ko * 8];
      acc_o = __builtin_amdgcn_mfma_f32_16x16x32_f16(pa, vf3, acc_o, 0, 0, 0);
    }
    if (c < 7) {
      sacc0 = (f32x4){};
      sacc1 = (f32x4){};
      sacc0 = __builtin_amdgcn_mfma_f32_16x16x32_f16(aq[0], kn00, sacc0, 0, 0, 0);
      sacc1 = __builtin_amdgcn_mfma_f32_16x16x32_f16(aq[0], kn01, sacc1, 0, 0, 0);
      sacc0 = __builtin_amdgcn_mfma_f32_16x16x32_f16(aq[1], kn10, sacc0, 0, 0, 0);
      sacc1 = __builtin_amdgcn_mfma_f32_16x16x32_f16(aq[1], kn11, sacc1, 0, 0, 0);
      vf0 = vn0; vf1 = vn1; vf2 = vn2; vf3 = vn3;
    }
  }

#pragma unroll
  for (int r = 0; r < 4; ++r)
    out[(size_t)(h * SEQ + rblk * 16 + (ko << 2) + r) * HD + dw + ln] = acc_o[r];
}

extern "C" void kernel_launch(void* const* d_in, const int* in_sizes, int n_in,
                              void* d_out, int out_size, void* d_ws, size_t ws_size,
                              hipStream_t stream) {
  const float* q = (const float*)d_in[0];
  const float* k = (const float*)d_in[1];
  const float* v = (const float*)d_in[2];
  (void)in_sizes; (void)n_in; (void)out_size; (void)ws_size;  // mask is all-False

  float* out = (float*)d_out;
  float* attn = out + (size_t)NH * SEQ * HD;  // second tuple output

  float* wsf = (float*)d_ws;   // 6*NHS vec + counter + pad + 3 fp16 tensors (~10 MB)
  float* vec = wsf;
  unsigned* cnt = (unsigned*)(wsf + 6 * NHS);
  __half* q16 = (__half*)(wsf + 6 * NHS + 64);
  __half* k16 = q16 + (size_t)NH * SEQ * HD;
  __half* vt16 = k16 + (size_t)NH * SEQ * HD;

  k_prep<<<2304, 256, 0, stream>>>(q, k, v, q16, k16, vt16, wsf);
  k_sink<<<GRID_SINK, 256, 0, stream>>>(q16, k16, vec, cnt);
  k_final<<<1536, 256, 0, stream>>>(q16, k16, vt16, vec + 4 * NHS, vec + 5 * NHS, attn, out);
}

// Round 11
// 146.901 us; speedup vs baseline: 2.6863x; 2.6863x over previous
//
#include <hip/hip_runtime.h>
#include <hip/hip_fp16.h>
#include <cstddef>
#include <cstdint>

// Sinkformer attention, B=2 H=12 S=1024 D=64, fp32 in/out.
// v7: fused-iteration Sinkhorn. Each k_iter launch = ONE Sinkhorn iteration:
// block owns a 16-row x 1024 P strip held in REGISTERS (f32x4 p[8][2] = 64
// VGPR; no launch_bounds cap -> no spill; r10's k_sink spilled because
// __launch_bounds__(256,4) capped VGPR at 64 while P needed 128 -> 100MB
// scratch traffic). Row-dot (b from csPrev) -> a = mu/rd local -> col partials
// from the same regs -> atomics. 3 iters + k_final = 4 P-computes total.
//   iter1 (b=1):  a1, cs0;  iter2: a2, cs1;  iter3: a3 (avec), cs2
//   k_final (r9 pipeline): attn = P*a3*(1/cs2); out = attn @ V.

#define NH 24
#define SEQ 1024
#define HD 64
#define NHS (NH * SEQ)

typedef _Float16 f16x8 __attribute__((ext_vector_type(8)));
typedef float f32x4 __attribute__((ext_vector_type(4)));

// prep: flat grid 2304 = 3*768. z=0: Q->Q16 (+zero cs0..cs2),
// z=1: K->K16, z=2: V->Vt16 (transpose via LDS).
__global__ __launch_bounds__(256) void k_prep(const float* __restrict__ q,
                                              const float* __restrict__ kin,
                                              const float* __restrict__ v,
                                              __half* __restrict__ q16,
                                              __half* __restrict__ k16,
                                              __half* __restrict__ vt16,
                                              float* __restrict__ zvec) {
  const int b = blockIdx.x;
  const int z = b / 768;
  const int bb = b - z * 768;
  const int t = threadIdx.x;
  if (z < 2) {
    const float* src = z ? kin : q;
    __half* dst = z ? k16 : q16;
    size_t u = ((size_t)bb * 256 + t) * 8;
    const float4* s4 = (const float4*)(src + u);
    float4 a = s4[0], c = s4[1];
    f16x8 h;
    h[0] = (_Float16)a.x; h[1] = (_Float16)a.y; h[2] = (_Float16)a.z; h[3] = (_Float16)a.w;
    h[4] = (_Float16)c.x; h[5] = (_Float16)c.y; h[6] = (_Float16)c.z; h[7] = (_Float16)c.w;
    *(f16x8*)(dst + u) = h;
    if (z == 0) {
      int gid = bb * 256 + t;
      if (gid < 3 * NHS) zvec[gid] = 0.f;  // cs0, cs1, cs2
    }
  } else {
    __shared__ float ld[64][33];
    const int h = bb >> 5, s0 = (bb & 31) << 5;  // 32-row slab of V
    const float* Vh = v + (size_t)h * SEQ * HD;
#pragma unroll
    for (int it = 0; it < 2; ++it) {
      int f = t + (it << 8);
      int r = f >> 4, c4 = (f & 15) << 2;
      float4 vv = *(const float4*)(Vh + (size_t)(s0 + r) * HD + c4);
      ld[c4 + 0][r] = vv.x; ld[c4 + 1][r] = vv.y;
      ld[c4 + 2][r] = vv.z; ld[c4 + 3][r] = vv.w;
    }
    __syncthreads();
    int d = t >> 2, sg = (t & 3) << 3;
    f16x8 h8;
#pragma unroll
    for (int i = 0; i < 8; ++i) h8[i] = (_Float16)ld[d][sg + i];
    *(f16x8*)(vt16 + (size_t)h * HD * SEQ + (size_t)d * SEQ + s0 + sg) = h8;
  }
}

// One Sinkhorn iteration, P strip in registers. Block = 16 rows, 4 waves;
// wave w owns cols cw+n*16 within each 128-col chunk. K-frag prefetch
// pipeline (r9-proven), no in-loop barriers.
// FIRST=1: b=1. Else b = (1/1024)/csPrev[col].
template <int FIRST>
__global__ __launch_bounds__(256) void k_iter(const __half* __restrict__ q16,
                                              const __half* __restrict__ k16,
                                              const float* __restrict__ csPrev,
                                              float* __restrict__ avecOut,
                                              float* __restrict__ csOut) {
  __shared__ float binv[1024];
  __shared__ float rdred[16][4];
  __shared__ float a_s[16];
  const int bid = blockIdx.x;
  const int swz = (bid & 7) * 192 + (bid >> 3);  // 1536 % 8 == 0: bijective
  const int h = swz >> 6;
  const int rblk = swz & 63;
  const int t = threadIdx.x;
  const int w = t >> 6, lane = t & 63, ln = lane & 15, ko = lane >> 4;
  const __half* qh = q16 + ((size_t)h << 16);
  const __half* kh = k16 + ((size_t)h << 16);

  if (!FIRST) {
#pragma unroll
    for (int i = 0; i < 4; ++i) {
      int idx = t + (i << 8);
      binv[idx] = (1.0f / 1024.0f) / csPrev[h * SEQ + idx];
    }
  }
  f16x8 aq[2];
#pragma unroll
  for (int kk = 0; kk < 2; ++kk)
    aq[kk] = *(const f16x8*)(qh + (size_t)(rblk * 16 + ln) * HD + kk * 32 + ko * 8);

  const int cw = w << 5;
  // prologue: chunk-0 K frags
  f16x8 kf00 = *(const f16x8*)(kh + (size_t)(cw + ln) * HD + ko * 8);
  f16x8 kf01 = *(const f16x8*)(kh + (size_t)(cw + 16 + ln) * HD + ko * 8);
  f16x8 kf10 = *(const f16x8*)(kh + (size_t)(cw + ln) * HD + 32 + ko * 8);
  f16x8 kf11 = *(const f16x8*)(kh + (size_t)(cw + 16 + ln) * HD + 32 + ko * 8);

  f32x4 p[8][2];  // 64 VGPR: P strip, exp'd
#pragma unroll
  for (int c = 0; c < 8; ++c) {
    f16x8 kn00, kn01, kn10, kn11;
    if (c < 7) {
      const __half* kb = kh + (size_t)((c + 1) << 7) * HD;
      kn00 = *(const f16x8*)(kb + (size_t)(cw + ln) * HD + ko * 8);
      kn01 = *(const f16x8*)(kb + (size_t)(cw + 16 + ln) * HD + ko * 8);
      kn10 = *(const f16x8*)(kb + (size_t)(cw + ln) * HD + 32 + ko * 8);
      kn11 = *(const f16x8*)(kb + (size_t)(cw + 16 + ln) * HD + 32 + ko * 8);
    }
    f32x4 s0 = {}, s1 = {};
    s0 = __builtin_amdgcn_mfma_f32_16x16x32_f16(aq[0], kf00, s0, 0, 0, 0);
    s1 = __builtin_amdgcn_mfma_f32_16x16x32_f16(aq[0], kf01, s1, 0, 0, 0);
    s0 = __builtin_amdgcn_mfma_f32_16x16x32_f16(aq[1], kf10, s0, 0, 0, 0);
    s1 = __builtin_amdgcn_mfma_f32_16x16x32_f16(aq[1], kf11, s1, 0, 0, 0);
#pragma unroll
    for (int r = 0; r < 4; ++r) {
      p[c][0][r] = __expf(s0[r] * 0.125f);
      p[c][1][r] = __expf(s1[r] * 0.125f);
    }
    if (c < 7) { kf00 = kn00; kf01 = kn01; kf10 = kn10; kf11 = kn11; }
  }
  __syncthreads();  // binv writes (pre-loop) visible to all

  // row-dot: rd_i = sum_j P_ij * b_j  (rows ko*4+r, this thread's 16 cols)
  float rsum[4] = {0.f, 0.f, 0.f, 0.f};
#pragma unroll
  for (int c = 0; c < 8; ++c)
#pragma unroll
    for (int n = 0; n < 2; ++n) {
      float bv = FIRST ? 1.0f : binv[(c << 7) + cw + n * 16 + ln];
#pragma unroll
      for (int r = 0; r < 4; ++r) rsum[r] += p[c][n][r] * bv;
    }
#pragma unroll
  for (int r = 0; r < 4; ++r) {
    float s = rsum[r];
    s += __shfl_xor(s, 1, 16); s += __shfl_xor(s, 2, 16);
    s += __shfl_xor(s, 4, 16); s += __shfl_xor(s, 8, 16);
    if (ln == 0) rdred[(ko << 2) + r][w] = s;
  }
  __syncthreads();
  if (t < 16) {
    float rd = rdred[t][0] + rdred[t][1] + rdred[t][2] + rdred[t][3];
    float a = (1.0f / 1024.0f) / rd;
    a_s[t] = a;
    avecOut[h * SEQ + rblk * 16 + t] = a;
  }
  __syncthreads();

  // col partials: cs_j += sum_i P_ij * a_i (16 strip rows fully local)
  float av[4];
#pragma unroll
  for (int r = 0; r < 4; ++r) av[r] = a_s[(ko << 2) + r];
#pragma unroll
  for (int c = 0; c < 8; ++c)
#pragma unroll
    for (int n = 0; n < 2; ++n) {
      float s = p[c][n][0] * av[0] + p[c][n][1] * av[1]
              + p[c][n][2] * av[2] + p[c][n][3] * av[3];
      s += __shfl_xor(s, 16);
      s += __shfl_xor(s, 32);
      if (lane < 16) atomicAdd(&csOut[h * SEQ + (c << 7) + cw + n * 16 + ln], s);
    }
}

// Final, pipelined (r9-proven): 16 rows/block, 4 waves. Per 128-col chunk
// (ONE barrier): [prefetch K/V frags c+1] [exp/scale sacc(c) -> ps16[c&1]] BAR
// [attn store] [PV(c): A=ps16, B=vf regs] [QK(c+1) -> sacc].
// a3 read directly from avec (computed by iter3).
__global__ __launch_bounds__(256) void k_final(const __half* __restrict__ q16,
                                               const __half* __restrict__ k16,
                                               const __half* __restrict__ vt16,
                                               const float* __restrict__ avec,
                                               const float* __restrict__ cs2,
                                               float* __restrict__ attn,
                                               float* __restrict__ out) {
  __shared__ __align__(16) __half ps16[2][16][136];
  __shared__ float binv[1024];
  __shared__ float a_s[16];
  const int bid = blockIdx.x;
  const int swz = (bid & 7) * 192 + (bid >> 3);   // bijective
  const int h = swz >> 6;
  const int rblk = swz & 63;
  const int t = threadIdx.x;
  const int w = t >> 6, lane = t & 63, ln = lane & 15, ko = lane >> 4;

#pragma unroll
  for (int i = 0; i < 4; ++i) {
    int idx = t + (i << 8);
    binv[idx] = 1.0f / cs2[h * SEQ + idx];
  }
  if (t < 16) a_s[t] = avec[h * SEQ + rblk * 16 + t];

  const __half* qh = q16 + ((size_t)h << 16);
  const __half* kh = k16 + ((size_t)h << 16);
  const __half* vth = vt16 + ((size_t)h << 16);
  f16x8 aq[2];
#pragma unroll
  for (int kk = 0; kk < 2; ++kk)
    aq[kk] = *(const f16x8*)(qh + (size_t)(rblk * 16 + ln) * HD + kk * 32 + ko * 8);

  const int cw = w << 5;   // wave's 32-col QK slice within the chunk
  const int dw = w << 4;   // wave's 16-d PV slice

  f16x8 kf00, kf01, kf10, kf11;
  kf00 = *(const f16x8*)(kh + (size_t)(cw + ln) * HD + ko * 8);
  kf01 = *(const f16x8*)(kh + (size_t)(cw + 16 + ln) * HD + ko * 8);
  kf10 = *(const f16x8*)(kh + (size_t)(cw + ln) * HD + 32 + ko * 8);
  kf11 = *(const f16x8*)(kh + (size_t)(cw + 16 + ln) * HD + 32 + ko * 8);
  f16x8 vf0, vf1, vf2, vf3;
  {
    const __half* vb = vth + (size_t)(dw + ln) * SEQ;
    vf0 = *(const f16x8*)(vb + ko * 8);
    vf1 = *(const f16x8*)(vb + 32 + ko * 8);
    vf2 = *(const f16x8*)(vb + 64 + ko * 8);
    vf3 = *(const f16x8*)(vb + 96 + ko * 8);
  }
  f32x4 sacc0 = {}, sacc1 = {};
  sacc0 = __builtin_amdgcn_mfma_f32_16x16x32_f16(aq[0], kf00, sacc0, 0, 0, 0);
  sacc1 = __builtin_amdgcn_mfma_f32_16x16x32_f16(aq[0], kf01, sacc1, 0, 0, 0);
  sacc0 = __builtin_amdgcn_mfma_f32_16x16x32_f16(aq[1], kf10, sacc0, 0, 0, 0);
  sacc1 = __builtin_amdgcn_mfma_f32_16x16x32_f16(aq[1], kf11, sacc1, 0, 0, 0);
  f32x4 acc_o = {};
  __syncthreads();  // binv / a_s ready

  for (int c = 0; c < 8; ++c) {
    const int j0 = c << 7;
    const int buf = c & 1;
    f16x8 kn00, kn01, kn10, kn11, vn0, vn1, vn2, vn3;
    if (c < 7) {
      const __half* kb = kh + (size_t)(j0 + 128) * HD;
      kn00 = *(const f16x8*)(kb + (size_t)(cw + ln) * HD + ko * 8);
      kn01 = *(const f16x8*)(kb + (size_t)(cw + 16 + ln) * HD + ko * 8);
      kn10 = *(const f16x8*)(kb + (size_t)(cw + ln) * HD + 32 + ko * 8);
      kn11 = *(const f16x8*)(kb + (size_t)(cw + 16 + ln) * HD + 32 + ko * 8);
      const __half* vb = vth + (size_t)(dw + ln) * SEQ + j0 + 128;
      vn0 = *(const f16x8*)(vb + ko * 8);
      vn1 = *(const f16x8*)(vb + 32 + ko * 8);
      vn2 = *(const f16x8*)(vb + 64 + ko * 8);
      vn3 = *(const f16x8*)(vb + 96 + ko * 8);
    }
#pragma unroll
    for (int r = 0; r < 4; ++r) {
      int row = (ko << 2) + r;
      int cA = cw + ln, cB = cw + 16 + ln;
      ps16[buf][row][cA] = __float2half(__expf(sacc0[r] * 0.125f) * a_s[row] * binv[j0 + cA]);
      ps16[buf][row][cB] = __float2half(__expf(sacc1[r] * 0.125f) * a_s[row] * binv[j0 + cB]);
    }
    __syncthreads();
    {
      int arow = t >> 4, cg = (t & 15) << 3;
      f16x8 hv = *(const f16x8*)&ps16[buf][arow][cg];
      f32x4 o0, o1;
#pragma unroll
      for (int i = 0; i < 4; ++i) { o0[i] = (float)hv[i]; o1[i] = (float)hv[4 + i]; }
      float* ap = attn + (size_t)(h * SEQ + rblk * 16 + arow) * SEQ + j0 + cg;
      *(f32x4*)ap = o0;
      *(f32x4*)(ap + 4) = o1;
    }
    {
      f16x8 pa;
      pa = *(const f16x8*)&ps16[buf][ln][ko * 8];
      acc_o = __builtin_amdgcn_mfma_f32_16x16x32_f16(pa, vf0, acc_o, 0, 0, 0);
      pa = *(const f16x8*)&ps16[buf][ln][32 + ko * 8];
      acc_o = __builtin_amdgcn_mfma_f32_16x16x32_f16(pa, vf1, acc_o, 0, 0, 0);
      pa = *(const f16x8*)&ps16[buf][ln][64 + ko * 8];
      acc_o = __builtin_amdgcn_mfma_f32_16x16x32_f16(pa, vf2, acc_o, 0, 0, 0);
      pa = *(const f16x8*)&ps16[buf][ln][96 + ko * 8];
      acc_o = __builtin_amdgcn_mfma_f32_16x16x32_f16(pa, vf3, acc_o, 0, 0, 0);
    }
    if (c < 7) {
      sacc0 = (f32x4){};
      sacc1 = (f32x4){};
      sacc0 = __builtin_amdgcn_mfma_f32_16x16x32_f16(aq[0], kn00, sacc0, 0, 0, 0);
      sacc1 = __builtin_amdgcn_mfma_f32_16x16x32_f16(aq[0], kn01, sacc1, 0, 0, 0);
      sacc0 = __builtin_amdgcn_mfma_f32_16x16x32_f16(aq[1], kn10, sacc0, 0, 0, 0);
      sacc1 = __builtin_amdgcn_mfma_f32_16x16x32_f16(aq[1], kn11, sacc1, 0, 0, 0);
      vf0 = vn0; vf1 = vn1; vf2 = vn2; vf3 = vn3;
    }
  }

#pragma unroll
  for (int r = 0; r < 4; ++r)
    out[(size_t)(h * SEQ + rblk * 16 + (ko << 2) + r) * HD + dw + ln] = acc_o[r];
}

extern "C" void kernel_launch(void* const* d_in, const int* in_sizes, int n_in,
                              void* d_out, int out_size, void* d_ws, size_t ws_size,
                              hipStream_t stream) {
  const float* q = (const float*)d_in[0];
  const float* k = (const float*)d_in[1];
  const float* v = (const float*)d_in[2];
  (void)in_sizes; (void)n_in; (void)out_size; (void)ws_size;  // mask is all-False

  float* out = (float*)d_out;
  float* attn = out + (size_t)NH * SEQ * HD;  // second tuple output

  float* wsf = (float*)d_ws;   // 6*NHS floats + 3 fp16 tensors (~10 MB)
  float* cs0 = wsf;            // zeroed by prep (3*NHS contiguous)
  float* cs1 = wsf + 1 * NHS;
  float* cs2 = wsf + 2 * NHS;
  float* avA = wsf + 3 * NHS;
  float* avB = wsf + 4 * NHS;
  float* avC = wsf + 5 * NHS;
  __half* q16 = (__half*)(wsf + 6 * NHS);
  __half* k16 = q16 + (size_t)NH * SEQ * HD;
  __half* vt16 = k16 + (size_t)NH * SEQ * HD;

  k_prep<<<2304, 256, 0, stream>>>(q, k, v, q16, k16, vt16, wsf);
  k_iter<1><<<1536, 256, 0, stream>>>(q16, k16, cs0, avA, cs0);  // a1, cs0
  k_iter<0><<<1536, 256, 0, stream>>>(q16, k16, cs0, avB, cs1);  // a2, cs1
  k_iter<0><<<1536, 256, 0, stream>>>(q16, k16, cs1, avC, cs2);  // a3, cs2
  k_final<<<1536, 256, 0, stream>>>(q16, k16, vt16, avC, cs2, attn, out);
}

// Round 12
// 134.358 us; speedup vs baseline: 2.9370x; 1.0934x over previous
//
#include <hip/hip_runtime.h>
#include <hip/hip_fp16.h>
#include <cstddef>
#include <cstdint>

// Sinkformer attention, B=2 H=12 S=1024 D=64, fp32 in/out.
// v8: r9's proven prep + 6 recompute-P sweeps, plus a BARRIER-FREE k_final:
// swapped QK^T (mfma(A=K,B=Q)) puts P in C-frags with lane = P-ROW, so the
// softmax scale, attn store, and PV A-frag are wave-local. P->A-frag transpose
// goes through a per-wave private LDS slice (same-wave ds_write/ds_read, no
// __syncthreads). Chunk loop has ZERO barriers (r8 evidence: k_final was
// latency-bound at 1.7TB/s write vs 6.9 achievable, chained by per-chunk
// barrier + LDS bounce). Per-wave partial out reduced once at kernel end.
//   rd0=rowsum(P); cs0=colsum(P^T a1); rd1=P b1; cs1=colsum(P^T a2);
//   rd2=P b2; cs2=colsum(P^T a3); attn = P*a3*(1/cs2); out = attn @ V.

#define NH 24
#define SEQ 1024
#define HD 64
#define NHS (NH * SEQ)

typedef _Float16 f16x8 __attribute__((ext_vector_type(8)));
typedef float f32x4 __attribute__((ext_vector_type(4)));

// prep: flat grid 2304 = 3*768. z=0: Q->Q16 (+zero rd0..cs2, 6*NHS),
// z=1: K->K16, z=2: V->Vt16 (transpose via LDS).
__global__ __launch_bounds__(256) void k_prep(const float* __restrict__ q,
                                              const float* __restrict__ kin,
                                              const float* __restrict__ v,
                                              __half* __restrict__ q16,
                                              __half* __restrict__ k16,
                                              __half* __restrict__ vt16,
                                              float* __restrict__ zvec) {
  const int b = blockIdx.x;
  const int z = b / 768;
  const int bb = b - z * 768;
  const int t = threadIdx.x;
  if (z < 2) {
    const float* src = z ? kin : q;
    __half* dst = z ? k16 : q16;
    size_t u = ((size_t)bb * 256 + t) * 8;
    const float4* s4 = (const float4*)(src + u);
    float4 a = s4[0], c = s4[1];
    f16x8 h;
    h[0] = (_Float16)a.x; h[1] = (_Float16)a.y; h[2] = (_Float16)a.z; h[3] = (_Float16)a.w;
    h[4] = (_Float16)c.x; h[5] = (_Float16)c.y; h[6] = (_Float16)c.z; h[7] = (_Float16)c.w;
    *(f16x8*)(dst + u) = h;
    if (z == 0) {
      int gid = bb * 256 + t;
      if (gid < 6 * NHS) zvec[gid] = 0.f;  // rd0,cs0,rd1,cs1,rd2,cs2
    }
  } else {
    __shared__ float ld[64][33];
    const int h = bb >> 5, s0 = (bb & 31) << 5;  // 32-row slab of V
    const float* Vh = v + (size_t)h * SEQ * HD;
#pragma unroll
    for (int it = 0; it < 2; ++it) {
      int f = t + (it << 8);
      int r = f >> 4, c4 = (f & 15) << 2;
      float4 vv = *(const float4*)(Vh + (size_t)(s0 + r) * HD + c4);
      ld[c4 + 0][r] = vv.x; ld[c4 + 1][r] = vv.y;
      ld[c4 + 2][r] = vv.z; ld[c4 + 3][r] = vv.w;
    }
    __syncthreads();
    int d = t >> 2, sg = (t & 3) << 3;
    f16x8 h8;
#pragma unroll
    for (int i = 0; i < 8; ++i) h8[i] = (_Float16)ld[d][sg + i];
    *(f16x8*)(vt16 + (size_t)h * HD * SEQ + (size_t)d * SEQ + s0 + sg) = h8;
  }
}

// Recompute-P sweep (r9-proven). 128x128 tile, 4 waves of 64x64. K staged in
// LDS, Q frags in regs (issued pre-barrier). One barrier.
// MODE 0: rdOut_i += sum_j P_ij
// MODE 1: rdOut_i += sum_j P_ij * b_j,  b = (1/1024)/vecPrev[col]
// MODE 2: csOut_j += sum_i P_ij * a_i,  a = (1/1024)/vecPrev[row]
template <int MODE>
__global__ __launch_bounds__(256) void k_sweep(const __half* __restrict__ q16,
                                               const __half* __restrict__ k16,
                                               const float* __restrict__ vecPrev,
                                               float* __restrict__ vecOut) {
  __shared__ __align__(16) __half ks[128][72];   // 18.4 KB
  __shared__ float ws_[128];
  const int bid = blockIdx.x;
  const int swz = (bid & 7) * 192 + (bid >> 3);   // 1536 % 8 == 0: bijective
  const int h = swz >> 6;
  const int row0 = ((swz >> 3) & 7) << 7;
  const int col0 = (swz & 7) << 7;
  const int t = threadIdx.x;
  const int w = t >> 6, lane = t & 63;
  const int ln = lane & 15, ko = lane >> 4;
  const int rb = (w & 1) << 6, cb = (w >> 1) << 6;
  const __half* qh = q16 + ((size_t)h << 16);
  const __half* kh = k16 + ((size_t)h << 16);

#pragma unroll
  for (int it = 0; it < 4; ++it) {
    int f = t + (it << 8);
    int row = f >> 3, c8 = (f & 7) << 3;
    *(f16x8*)&ks[row][c8] = *(const f16x8*)(kh + (size_t)(col0 + row) * HD + c8);
  }
  if (MODE == 1 && t < 128) ws_[t] = (1.0f / 1024.0f) / vecPrev[h * SEQ + col0 + t];
  if (MODE == 2 && t < 128) ws_[t] = (1.0f / 1024.0f) / vecPrev[h * SEQ + row0 + t];
  f16x8 af[4][2];
#pragma unroll
  for (int m = 0; m < 4; ++m)
#pragma unroll
    for (int kk = 0; kk < 2; ++kk)
      af[m][kk] = *(const f16x8*)(qh + (size_t)(row0 + rb + m * 16 + ln) * HD + kk * 32 + ko * 8);
  __syncthreads();

  f32x4 acc[4][4] = {};
#pragma unroll
  for (int kk = 0; kk < 2; ++kk) {
    f16x8 bf[4];
#pragma unroll
    for (int n = 0; n < 4; ++n)
      bf[n] = *(const f16x8*)&ks[cb + n * 16 + ln][kk * 32 + ko * 8];
#pragma unroll
    for (int m = 0; m < 4; ++m)
#pragma unroll
      for (int n = 0; n < 4; ++n)
        acc[m][n] = __builtin_amdgcn_mfma_f32_16x16x32_f16(af[m][kk], bf[n], acc[m][n], 0, 0, 0);
  }

#pragma unroll
  for (int m = 0; m < 4; ++m)
#pragma unroll
    for (int n = 0; n < 4; ++n)
#pragma unroll
      for (int r = 0; r < 4; ++r)
        acc[m][n][r] = __expf(acc[m][n][r] * 0.125f);

  if (MODE == 2) {
    float* cs = vecOut + h * SEQ;
#pragma unroll
    for (int n = 0; n < 4; ++n) {
      float s = 0.f;
#pragma unroll
      for (int m = 0; m < 4; ++m)
#pragma unroll
        for (int r = 0; r < 4; ++r)
          s += acc[m][n][r] * ws_[rb + m * 16 + (ko << 2) + r];
      s += __shfl_xor(s, 16);
      s += __shfl_xor(s, 32);
      if (lane < 16) atomicAdd(&cs[col0 + cb + n * 16 + ln], s);
    }
  } else {
    float* rd = vecOut + h * SEQ;
#pragma unroll
    for (int m = 0; m < 4; ++m)
#pragma unroll
      for (int r = 0; r < 4; ++r) {
        float s;
        if (MODE == 1) {
          s = acc[m][0][r] * ws_[cb + ln] + acc[m][1][r] * ws_[cb + 16 + ln]
            + acc[m][2][r] * ws_[cb + 32 + ln] + acc[m][3][r] * ws_[cb + 48 + ln];
        } else {
          s = acc[m][0][r] + acc[m][1][r] + acc[m][2][r] + acc[m][3][r];
        }
        s += __shfl_xor(s, 1, 16); s += __shfl_xor(s, 2, 16);
        s += __shfl_xor(s, 4, 16); s += __shfl_xor(s, 8, 16);
        if (ln == 0) atomicAdd(&rd[row0 + rb + m * 16 + (ko << 2) + r], s);
      }
  }
}

// Final v5, barrier-free chunk loop. Block = 16-row strip, 4 waves; wave w
// owns cols [w*256, w*256+256) in 8 windows of 32.
// Per window: swapped QK (A=K, B=Q) -> C-frag lane ln = P-ROW, regs = cols
// ko*4+r; exp * a3[row] * binv[col]; attn f32x4 store (64B/row segments);
// pack fp16 -> per-wave LDS slice; read back as PV A-frag (same wave, no
// barrier); 4 PV mfma into per-wave partial out. End: cross-wave out reduce.
__global__ __launch_bounds__(256) void k_final(const __half* __restrict__ q16,
                                               const __half* __restrict__ k16,
                                               const __half* __restrict__ vt16,
                                               const float* __restrict__ rd2,
                                               const float* __restrict__ cs2,
                                               float* __restrict__ attn,
                                               float* __restrict__ out) {
  __shared__ float binv[1024];
  __shared__ __align__(16) __half ps[4][16][32];    // per-wave transpose slice
  __shared__ __align__(16) float ored[4][16][68];   // out reduction
  const int bid = blockIdx.x;
  const int swz = (bid & 7) * 192 + (bid >> 3);     // bijective
  const int h = swz >> 6;
  const int rblk = swz & 63;
  const int grow0 = h * SEQ + (rblk << 4);
  const int t = threadIdx.x;
  const int w = t >> 6, lane = t & 63, ln = lane & 15, ko = lane >> 4;

#pragma unroll
  for (int i = 0; i < 4; ++i) {
    int idx = t + (i << 8);
    binv[idx] = 1.0f / cs2[h * SEQ + idx];
  }
  const float a_reg = (1.0f / 1024.0f) / rd2[grow0 + ln];  // this lane's row scale

  const __half* qh = q16 + ((size_t)h << 16);
  const __half* kh = k16 + ((size_t)h << 16);
  const __half* vth = vt16 + ((size_t)h << 16);
  f16x8 aq[2];
#pragma unroll
  for (int kk = 0; kk < 2; ++kk)
    aq[kk] = *(const f16x8*)(qh + (size_t)((rblk << 4) + ln) * HD + kk * 32 + ko * 8);

  f32x4 acc_o[4] = {};  // PV partial: acc_o[dt], lane ln = d-local, reg = row ko*4+r
  __syncthreads();      // binv ready

#pragma unroll
  for (int win = 0; win < 8; ++win) {
    const int c0 = (w << 8) + (win << 5);
    // swapped QK^T: sacc_s covers P rows (lane ln), cols c0+s*16+ko*4+{0..3}
    f32x4 sacc0 = {}, sacc1 = {};
    {
      f16x8 ka;
      ka = *(const f16x8*)(kh + (size_t)(c0 + ln) * HD + ko * 8);
      sacc0 = __builtin_amdgcn_mfma_f32_16x16x32_f16(ka, aq[0], sacc0, 0, 0, 0);
      ka = *(const f16x8*)(kh + (size_t)(c0 + ln) * HD + 32 + ko * 8);
      sacc0 = __builtin_amdgcn_mfma_f32_16x16x32_f16(ka, aq[1], sacc0, 0, 0, 0);
      ka = *(const f16x8*)(kh + (size_t)(c0 + 16 + ln) * HD + ko * 8);
      sacc1 = __builtin_amdgcn_mfma_f32_16x16x32_f16(ka, aq[0], sacc1, 0, 0, 0);
      ka = *(const f16x8*)(kh + (size_t)(c0 + 16 + ln) * HD + 32 + ko * 8);
      sacc1 = __builtin_amdgcn_mfma_f32_16x16x32_f16(ka, aq[1], sacc1, 0, 0, 0);
    }
    // scale -> attn store + fp16 pack into per-wave LDS slice
#pragma unroll
    for (int s = 0; s < 2; ++s) {
      f32x4 sc = s ? sacc1 : sacc0;
      const int colb = c0 + s * 16 + (ko << 2);
      float4 bv = *(const float4*)&binv[colb];
      f32x4 att;
      att[0] = __expf(sc[0] * 0.125f) * a_reg * bv.x;
      att[1] = __expf(sc[1] * 0.125f) * a_reg * bv.y;
      att[2] = __expf(sc[2] * 0.125f) * a_reg * bv.z;
      att[3] = __expf(sc[3] * 0.125f) * a_reg * bv.w;
      *(f32x4*)(attn + (size_t)(grow0 + ln) * SEQ + colb) = att;
      __half2 h0 = __floats2half2_rn(att[0], att[1]);
      __half2 h1 = __floats2half2_rn(att[2], att[3]);
      uint2 hp;
      hp.x = *(const uint*)&h0;
      hp.y = *(const uint*)&h1;
      *(uint2*)&ps[w][ln][s * 16 + (ko << 2)] = hp;
    }
    // PV: A-frag from same-wave LDS slice (lane ln = row, 8 window-local cols)
    f16x8 pa = *(const f16x8*)&ps[w][ln][ko * 8];
#pragma unroll
    for (int dt = 0; dt < 4; ++dt) {
      f16x8 vb = *(const f16x8*)(vth + (size_t)(dt * 16 + ln) * SEQ + c0 + ko * 8);
      acc_o[dt] = __builtin_amdgcn_mfma_f32_16x16x32_f16(pa, vb, acc_o[dt], 0, 0, 0);
    }
  }

  // cross-wave out reduction: ored[w][row][d]
#pragma unroll
  for (int dt = 0; dt < 4; ++dt)
#pragma unroll
    for (int r = 0; r < 4; ++r)
      ored[w][(ko << 2) + r][dt * 16 + ln] = acc_o[dt][r];
  __syncthreads();
  {
    const int row = t >> 4, d4 = (t & 15) << 2;
    f32x4 s = {};
#pragma unroll
    for (int ww = 0; ww < 4; ++ww) {
      float4 v4 = *(const float4*)&ored[ww][row][d4];
      s[0] += v4.x; s[1] += v4.y; s[2] += v4.z; s[3] += v4.w;
    }
    *(f32x4*)(out + (size_t)(grow0 + row) * HD + d4) = s;
  }
}

extern "C" void kernel_launch(void* const* d_in, const int* in_sizes, int n_in,
                              void* d_out, int out_size, void* d_ws, size_t ws_size,
                              hipStream_t stream) {
  const float* q = (const float*)d_in[0];
  const float* k = (const float*)d_in[1];
  const float* v = (const float*)d_in[2];
  (void)in_sizes; (void)n_in; (void)out_size; (void)ws_size;  // mask is all-False

  float* out = (float*)d_out;
  float* attn = out + (size_t)NH * SEQ * HD;  // second tuple output

  float* wsf = (float*)d_ws;   // 6*NHS floats + 3 fp16 tensors (~10 MB)
  float* rd0 = wsf;            // zeroed by prep (6*NHS contiguous)
  float* cs0 = wsf + 1 * NHS;
  float* rd1 = wsf + 2 * NHS;
  float* cs1 = wsf + 3 * NHS;
  float* rd2 = wsf + 4 * NHS;
  float* cs2 = wsf + 5 * NHS;
  __half* q16 = (__half*)(wsf + 6 * NHS);
  __half* k16 = q16 + (size_t)NH * SEQ * HD;
  __half* vt16 = k16 + (size_t)NH * SEQ * HD;

  k_prep<<<2304, 256, 0, stream>>>(q, k, v, q16, k16, vt16, wsf);
  k_sweep<0><<<1536, 256, 0, stream>>>(q16, k16, rd0, rd0);   // rd0 = rowsum(P)
  k_sweep<2><<<1536, 256, 0, stream>>>(q16, k16, rd0, cs0);   // cs0 = colsum(P^T a1)
  k_sweep<1><<<1536, 256, 0, stream>>>(q16, k16, cs0, rd1);   // rd1 = P b1
  k_sweep<2><<<1536, 256, 0, stream>>>(q16, k16, rd1, cs1);   // cs1 = colsum(P^T a2)
  k_sweep<1><<<1536, 256, 0, stream>>>(q16, k16, cs1, rd2);   // rd2 = P b2
  k_sweep<2><<<1536, 256, 0, stream>>>(q16, k16, rd2, cs2);   // cs2 = colsum(P^T a3)
  k_final<<<1536, 256, 0, stream>>>(q16, k16, vt16, rd2, cs2, attn, out);
}